// Round 8
// baseline (643.873 us; speedup 1.0000x reference)
//
#include <hip/hip_runtime.h>
#include <stdint.h>

typedef unsigned short u16;
typedef __attribute__((ext_vector_type(8))) short short8;
typedef __attribute__((ext_vector_type(16))) float floatx16;

#define M_TOTAL 16384   // BATCH*SEQ
#define DM 512
#define NRULES 16
#define BK 64

__device__ __forceinline__ u16 f2bf(float f) {
  uint32_t u = __float_as_uint(f);
  u += 0x7fffu + ((u >> 16) & 1u);   // RNE
  return (u16)(u >> 16);
}

__device__ __forceinline__ void gld_lds16(const u16* g, u16* l) {
  __builtin_amdgcn_global_load_lds(
      (const __attribute__((address_space(1))) void*)g,
      (__attribute__((address_space(3))) void*)l, 16, 0, 0);
}

// Stage 32 rows x 64 cols bf16 into LDS (p1 path, BK=64).
// Physical chunk slot p of row r holds logical chunk p^(r&7); readers apply
// the same XOR.  Quarter-wave b128 reads -> 2-way bank aliasing = free (m136).
__device__ __forceinline__ void stage32x64(const u16* __restrict__ src, int ld,
                                           int r0, int k0, u16* lds, int tid) {
  const int row = tid >> 3, p = tid & 7;
  const int g = p ^ (row & 7);
  gld_lds16(src + (size_t)(r0 + row) * ld + k0 + g * 8, lds + tid * 8);
}

// Stage 16 rows x 128 cols bf16 into LDS (p2 path, BK=128).
__device__ __forceinline__ void stage16x128(const u16* __restrict__ src, int ld,
                                            int r0, int k0, u16* lds, int tid) {
  const int row = tid >> 4, p = tid & 15;
  const int g = p ^ (row & 7);
  gld_lds16(src + (size_t)(r0 + row) * ld + k0 + g * 8, lds + tid * 8);
}

// ---------------- conversion kernels ----------------

__global__ __launch_bounds__(256) void convert_x(const float* __restrict__ x,
                                                 u16* __restrict__ X,
                                                 float* __restrict__ cond) {
  const int gid = blockIdx.x * 256 + threadIdx.x;
  if (gid < NRULES * 4 * DM) cond[gid] = 0.f;   // zero cond accumulators (ws poisoned)
  const int n4 = M_TOTAL * DM / 4;
  for (int i = gid; i < n4; i += gridDim.x * 256) {
    float4 v = ((const float4*)x)[i];
    ushort4 o;
    o.x = f2bf(v.x); o.y = f2bf(v.y); o.z = f2bf(v.z); o.w = f2bf(v.w);
    ((ushort4*)X)[i] = o;
  }
}

// 48 matrices [512][512] fp32 (k-major) -> bf16 transposed [n][k].
// WT slots: 0..15 = Wc^T, 16..31 = Wa1^T, 32..47 = Wa2^T.
__global__ __launch_bounds__(256) void transpose_w(const float* __restrict__ Wc,
                                                   const float* __restrict__ Wa1,
                                                   const float* __restrict__ Wa2,
                                                   u16* __restrict__ WT) {
  __shared__ u16 tile[64][68];
  const int bx = blockIdx.x;            // 48*64
  const int m = bx >> 6, t = bx & 63;
  const int tr = t >> 3, tc = t & 7;    // 64x64 tile at (k=tr*64, n=tc*64)
  const float* src = (m < 16 ? Wc : (m < 32 ? Wa1 : Wa2)) + (size_t)(m & 15) * (DM * DM);
  const int tid = threadIdx.x;
#pragma unroll
  for (int rep = 0; rep < 16; rep++) {
    const int idx = rep * 256 + tid;
    const int kr = idx >> 6, nc = idx & 63;
    tile[kr][nc] = f2bf(src[(size_t)(tr * 64 + kr) * DM + tc * 64 + nc]);
  }
  __syncthreads();
  u16* dst = WT + (size_t)m * (DM * DM);
#pragma unroll
  for (int rep = 0; rep < 16; rep++) {
    const int idx = rep * 256 + tid;
    const int nr = idx >> 6, kc = idx & 63;
    dst[(size_t)(tc * 64 + nr) * DM + tr * 64 + kc] = tile[kc][nr];
  }
}

// W2s[g][b][n][k] = bf16( Wa2T[ruleBase+g][n][k] * cond[ruleBase+g][b][n] / 4096 )
__global__ __launch_bounds__(256) void scale_w2(const u16* __restrict__ WT,
                                                const float* __restrict__ cond,
                                                u16* __restrict__ W2s,
                                                int ruleBase, int G) {
  const int total = G * 4 * DM * (DM / 8);
  for (int idx = blockIdx.x * 256 + threadIdx.x; idx < total; idx += gridDim.x * 256) {
    const int k8 = idx & 63;
    const int n  = (idx >> 6) & (DM - 1);
    const int gb = idx >> 15;            // g*4+b   (64*512 = 2^15)
    const int g = gb >> 2, b = gb & 3, rule = ruleBase + g;
    const float c = cond[((size_t)rule * 4 + b) * DM + n] * (1.0f / 4096.0f);
    const uint4 w = *(const uint4*)&WT[((size_t)(32 + rule)) * DM * DM + (size_t)n * DM + k8 * 8];
    uint4 o;
    {
      uint32_t u;
      u = w.x; o.x = (uint32_t)f2bf(__uint_as_float(u << 16) * c) | ((uint32_t)f2bf(__uint_as_float(u & 0xffff0000u) * c) << 16);
      u = w.y; o.y = (uint32_t)f2bf(__uint_as_float(u << 16) * c) | ((uint32_t)f2bf(__uint_as_float(u & 0xffff0000u) * c) << 16);
      u = w.z; o.z = (uint32_t)f2bf(__uint_as_float(u << 16) * c) | ((uint32_t)f2bf(__uint_as_float(u & 0xffff0000u) * c) << 16);
      u = w.w; o.w = (uint32_t)f2bf(__uint_as_float(u << 16) * c) | ((uint32_t)f2bf(__uint_as_float(u & 0xffff0000u) * c) << 16);
    }
    *(uint4*)&W2s[(size_t)gb * DM * DM + (size_t)n * DM + k8 * 8] = o;
  }
}

// ---------------- phase 1: cond partial sums + H = silu(x@Wa1) ----------------
// 128x128 tile, 4 waves 2x2, BK=64.  32x32x16 MFMA: wave tile 64x64 = 2x2
// tiles of 32x32, acc floatx16[2][2] (64 AGPRs, same as 4x4 f32x4).
// A/B lane map: row/col = lane&31, k = (lane>>5)*8 + j.
// C/D [m74/m101]: col = lane&31, row = (reg&3) + 8*(reg>>2) + 4*(lane>>5).

__global__ __launch_bounds__(256, 3) void p1_kernel(const u16* __restrict__ X,
                                                    const u16* __restrict__ WT,
                                                    const float* __restrict__ bc,
                                                    const float* __restrict__ ba1,
                                                    float* __restrict__ cond,
                                                    u16* __restrict__ H, int ruleBase) {
  __shared__ __attribute__((aligned(16))) u16 ldsA[128 * 64];
  __shared__ __attribute__((aligned(16))) u16 ldsB[128 * 64];
  const int tid = threadIdx.x;
  const int lane = tid & 63, wid = tid >> 6;
  const int waveM = wid >> 1, waveN = wid & 1;
  const int m0 = blockIdx.x * 128;
  const int nb = blockIdx.y;
  const int z = blockIdx.z;
  const int rule = ruleBase + z;
  const bool is_cond = nb < 4;
  const int n0 = (is_cond ? nb : nb - 4) * 128;
  const u16* B = WT + (size_t)(is_cond ? rule : 16 + rule) * (DM * DM);

  floatx16 acc[2][2];
#pragma unroll
  for (int i = 0; i < 2; i++)
#pragma unroll
    for (int j = 0; j < 2; j++) acc[i][j] = (floatx16)0.0f;

  const int l31 = lane & 31, lg = lane >> 5;

  for (int k0 = 0; k0 < DM; k0 += BK) {
    __syncthreads();
#pragma unroll
    for (int q = 0; q < 4; q++) stage32x64(X, DM, m0 + 32 * q, k0, ldsA + q * 2048, tid);
#pragma unroll
    for (int q = 0; q < 4; q++) stage32x64(B, DM, n0 + 32 * q, k0, ldsB + q * 2048, tid);
    __syncthreads();
#pragma unroll
    for (int s = 0; s < 4; s++) {
      const int c = s * 2 + lg;
      short8 a[2], bb[2];
#pragma unroll
      for (int i = 0; i < 2; i++) {
        const int row = waveM * 64 + i * 32 + l31;
        a[i] = *(const short8*)&ldsA[row * 64 + ((c ^ (row & 7)) * 8)];
      }
#pragma unroll
      for (int j = 0; j < 2; j++) {
        const int row = waveN * 64 + j * 32 + l31;
        bb[j] = *(const short8*)&ldsB[row * 64 + ((c ^ (row & 7)) * 8)];
      }
#pragma unroll
      for (int i = 0; i < 2; i++)
#pragma unroll
        for (int j = 0; j < 2; j++)
          acc[i][j] = __builtin_amdgcn_mfma_f32_32x32x16_bf16(a[i], bb[j], acc[i][j], 0, 0, 0);
    }
  }

  if (is_cond) {
    const int b = m0 >> 12;   // 128-row block lies within one batch
    float s[2];
#pragma unroll
    for (int j = 0; j < 2; j++) {
      const int col = n0 + waveN * 64 + j * 32 + l31;
      const float bias = bc[rule * DM + col];
      float tsum = 0.f;
#pragma unroll
      for (int i = 0; i < 2; i++)
#pragma unroll
        for (int r = 0; r < 16; r++)
          tsum += __builtin_amdgcn_rcpf(1.0f + __expf(-(acc[i][j][r] + bias)));
      s[j] = tsum;
    }
#pragma unroll
    for (int j = 0; j < 2; j++) s[j] += __shfl_xor(s[j], 32);
    if (lg == 0) {
#pragma unroll
      for (int j = 0; j < 2; j++) {
        const int col = n0 + waveN * 64 + j * 32 + l31;
        atomicAdd(&cond[((size_t)rule * 4 + b) * DM + col], s[j]);
      }
    }
  } else {
    u16* Hr = H + (size_t)z * M_TOTAL * DM;
#pragma unroll
    for (int i = 0; i < 2; i++)
#pragma unroll
      for (int j = 0; j < 2; j++) {
        const int col = n0 + waveN * 64 + j * 32 + l31;
        const float bias = ba1[rule * DM + col];
#pragma unroll
        for (int r = 0; r < 16; r++) {
          const int row = m0 + waveM * 64 + i * 32 + (r & 3) + 8 * (r >> 2) + 4 * lg;
          const float v = acc[i][j][r] + bias;
          Hr[(size_t)row * DM + col] = f2bf(v * __builtin_amdgcn_rcpf(1.0f + __expf(-v)));
        }
      }
  }
}

// ---------------- phase 2: out (+)= sum_g H_g @ W2s_g + sum_g cond_g*ba2_g ----------------
// W2s pre-scaled by cond/4096 -> one fused accumulator, K_eff = G*512.
// 128x128 tile, BK=128 (R7 win: halves barrier drains; 64 KB LDS free at the
// 512-block grid's 2 blocks/CU).  32x32x16 MFMA as in p1.

__global__ __launch_bounds__(256, 2) void p2_kernel(const u16* __restrict__ H,
                                                    const u16* __restrict__ W2s,
                                                    const float* __restrict__ ba2,
                                                    const float* __restrict__ cond,
                                                    float* __restrict__ out,
                                                    int ruleBase, int G, int accumulate) {
  __shared__ __attribute__((aligned(16))) u16 ldsA[128 * 128];   // 32 KB
  __shared__ __attribute__((aligned(16))) u16 ldsB[128 * 128];   // 32 KB
  const int tid = threadIdx.x;
  const int lane = tid & 63, wid = tid >> 6;
  const int waveM = wid >> 1, waveN = wid & 1;
  const int m0 = blockIdx.x * 128;
  const int n0 = blockIdx.y * 128;
  const int b = m0 >> 12;
  const int l31 = lane & 31, lg = lane >> 5;

  floatx16 acc[2][2];
#pragma unroll
  for (int i = 0; i < 2; i++)
#pragma unroll
    for (int j = 0; j < 2; j++) acc[i][j] = (floatx16)0.0f;

  for (int g = 0; g < G; g++) {
    const u16* A = H + (size_t)g * M_TOTAL * DM;
    const u16* Bp = W2s + (size_t)(g * 4 + b) * (DM * DM);
    for (int k0 = 0; k0 < DM; k0 += 128) {
      __syncthreads();
#pragma unroll
      for (int q = 0; q < 8; q++) stage16x128(A, DM, m0 + 16 * q, k0, ldsA + q * 2048, tid);
#pragma unroll
      for (int q = 0; q < 8; q++) stage16x128(Bp, DM, n0 + 16 * q, k0, ldsB + q * 2048, tid);
      __syncthreads();
#pragma unroll
      for (int s = 0; s < 8; s++) {
        const int c = s * 2 + lg;
        short8 a[2], bb[2];
#pragma unroll
        for (int i = 0; i < 2; i++) {
          const int row = waveM * 64 + i * 32 + l31;
          a[i] = *(const short8*)&ldsA[row * 128 + ((c ^ (row & 7)) * 8)];
        }
#pragma unroll
        for (int j = 0; j < 2; j++) {
          const int row = waveN * 64 + j * 32 + l31;
          bb[j] = *(const short8*)&ldsB[row * 128 + ((c ^ (row & 7)) * 8)];
        }
#pragma unroll
        for (int i = 0; i < 2; i++)
#pragma unroll
          for (int j = 0; j < 2; j++)
            acc[i][j] = __builtin_amdgcn_mfma_f32_32x32x16_bf16(a[i], bb[j], acc[i][j], 0, 0, 0);
      }
    }
  }

#pragma unroll
  for (int j = 0; j < 2; j++) {
    const int col = n0 + waveN * 64 + j * 32 + l31;
    float bt = 0.f;
    for (int g = 0; g < G; g++) {
      const int rule = ruleBase + g;
      bt += cond[((size_t)rule * 4 + b) * DM + col] * ba2[rule * DM + col];
    }
    bt *= (1.0f / 4096.0f);
#pragma unroll
    for (int i = 0; i < 2; i++)
#pragma unroll
      for (int r = 0; r < 16; r++) {
        const int row = m0 + waveM * 64 + i * 32 + (r & 3) + 8 * (r >> 2) + 4 * lg;
        const size_t idx = (size_t)row * DM + col;
        const float v = acc[i][j][r] + bt;
        out[idx] = accumulate ? (out[idx] + v) : v;
      }
  }
}

// ---------------- launch ----------------

extern "C" void kernel_launch(void* const* d_in, const int* in_sizes, int n_in,
                              void* d_out, int out_size, void* d_ws, size_t ws_size,
                              hipStream_t stream) {
  const float* x   = (const float*)d_in[0];
  const float* Wc  = (const float*)d_in[1];
  const float* bc  = (const float*)d_in[2];
  const float* Wa1 = (const float*)d_in[3];
  const float* ba1 = (const float*)d_in[4];
  const float* Wa2 = (const float*)d_in[5];
  const float* ba2 = (const float*)d_in[6];
  float* out = (float*)d_out;

  char* ws = (char*)d_ws;
  const size_t xBytes = (size_t)M_TOTAL * DM * 2;          // 16.78 MB
  const size_t wtBytes = (size_t)48 * DM * DM * 2;         // 25.17 MB
  const size_t condBytes = (size_t)NRULES * 4 * DM * 4;    // 128 KB
  const size_t fixed = xBytes + wtBytes + condBytes;
  const size_t hSlice = (size_t)M_TOTAL * DM * 2;          // 16.78 MB
  const size_t w2sSlice = (size_t)4 * DM * DM * 2;         // 2.10 MB per rule

  int G = 1;
  const int cand[5] = {16, 8, 4, 2, 1};
  for (int i = 0; i < 5; i++) {
    if (fixed + (size_t)cand[i] * (hSlice + w2sSlice) <= ws_size) { G = cand[i]; break; }
  }

  u16* X      = (u16*)ws;
  u16* WT     = (u16*)(ws + xBytes);
  float* cond = (float*)(ws + xBytes + wtBytes);
  u16* W2s    = (u16*)(ws + fixed);
  u16* H      = (u16*)(ws + fixed + (size_t)G * w2sSlice);

  convert_x<<<dim3(2048), dim3(256), 0, stream>>>(x, X, cond);
  transpose_w<<<dim3(48 * 64), dim3(256), 0, stream>>>(Wc, Wa1, Wa2, WT);

  for (int rb = 0; rb < NRULES; rb += G) {
    p1_kernel<<<dim3(128, 8, G), dim3(256), 0, stream>>>(X, WT, bc, ba1, cond, H, rb);
    scale_w2<<<dim3(2048), dim3(256), 0, stream>>>(WT, cond, W2s, rb, G);
    p2_kernel<<<dim3(128, 4), dim3(256), 0, stream>>>(H, W2s, ba2, cond, out, rb, G, rb > 0 ? 1 : 0);
  }
}

// Round 9
// 613.773 us; speedup vs baseline: 1.0490x; 1.0490x over previous
//
#include <hip/hip_runtime.h>
#include <stdint.h>

typedef unsigned short u16;
typedef __attribute__((ext_vector_type(8))) short short8;
typedef __attribute__((ext_vector_type(16))) float floatx16;

#define M_TOTAL 16384   // BATCH*SEQ
#define DM 512
#define NRULES 16
#define BK 64

__device__ __forceinline__ u16 f2bf(float f) {
  uint32_t u = __float_as_uint(f);
  u += 0x7fffu + ((u >> 16) & 1u);   // RNE
  return (u16)(u >> 16);
}

__device__ __forceinline__ void gld_lds16(const u16* g, u16* l) {
  __builtin_amdgcn_global_load_lds(
      (const __attribute__((address_space(1))) void*)g,
      (__attribute__((address_space(3))) void*)l, 16, 0, 0);
}

// LDS chunk swizzle: physical chunk slot p of row r holds logical chunk
// p ^ SW(r), SW(r) = (r>>1)&7.  Under BOTH phase models for ds_read_b128
// (16-consecutive-lane and even/odd-lane grouping) a fragment read with one
// logical chunk across 32 rows spreads 2-way over all 32 banks = free (m136).
// R8's SW(r)=r&7 was 4-way in the even/odd phases (4 extra cyc/b128, measured
// 1.678e7 conflict cycles); R7's 16x16 pattern was accidentally immune.
#define SW(r) (((r) >> 1) & 7)

// Stage 32 rows x 64 cols bf16 into LDS (p1 path, BK=64).
__device__ __forceinline__ void stage32x64(const u16* __restrict__ src, int ld,
                                           int r0, int k0, u16* lds, int tid) {
  const int row = tid >> 3, p = tid & 7;
  const int g = p ^ SW(row);
  gld_lds16(src + (size_t)(r0 + row) * ld + k0 + g * 8, lds + tid * 8);
}

// Stage 16 rows x 128 cols bf16 into LDS (p2 path, BK=128).  16 chunks/row;
// SW touches only low 3 bits so bank group = ((c^SW)&7)*4 spreads the same.
__device__ __forceinline__ void stage16x128(const u16* __restrict__ src, int ld,
                                            int r0, int k0, u16* lds, int tid) {
  const int row = tid >> 4, p = tid & 15;
  const int g = p ^ SW(row);
  gld_lds16(src + (size_t)(r0 + row) * ld + k0 + g * 8, lds + tid * 8);
}

// ---------------- conversion kernels ----------------

__global__ __launch_bounds__(256) void convert_x(const float* __restrict__ x,
                                                 u16* __restrict__ X,
                                                 float* __restrict__ cond) {
  const int gid = blockIdx.x * 256 + threadIdx.x;
  if (gid < NRULES * 4 * DM) cond[gid] = 0.f;   // zero cond accumulators (ws poisoned)
  const int n4 = M_TOTAL * DM / 4;
  for (int i = gid; i < n4; i += gridDim.x * 256) {
    float4 v = ((const float4*)x)[i];
    ushort4 o;
    o.x = f2bf(v.x); o.y = f2bf(v.y); o.z = f2bf(v.z); o.w = f2bf(v.w);
    ((ushort4*)X)[i] = o;
  }
}

// 48 matrices [512][512] fp32 (k-major) -> bf16 transposed [n][k].
// WT slots: 0..15 = Wc^T, 16..31 = Wa1^T, 32..47 = Wa2^T.
__global__ __launch_bounds__(256) void transpose_w(const float* __restrict__ Wc,
                                                   const float* __restrict__ Wa1,
                                                   const float* __restrict__ Wa2,
                                                   u16* __restrict__ WT) {
  __shared__ u16 tile[64][68];
  const int bx = blockIdx.x;            // 48*64
  const int m = bx >> 6, t = bx & 63;
  const int tr = t >> 3, tc = t & 7;    // 64x64 tile at (k=tr*64, n=tc*64)
  const float* src = (m < 16 ? Wc : (m < 32 ? Wa1 : Wa2)) + (size_t)(m & 15) * (DM * DM);
  const int tid = threadIdx.x;
#pragma unroll
  for (int rep = 0; rep < 16; rep++) {
    const int idx = rep * 256 + tid;
    const int kr = idx >> 6, nc = idx & 63;
    tile[kr][nc] = f2bf(src[(size_t)(tr * 64 + kr) * DM + tc * 64 + nc]);
  }
  __syncthreads();
  u16* dst = WT + (size_t)m * (DM * DM);
#pragma unroll
  for (int rep = 0; rep < 16; rep++) {
    const int idx = rep * 256 + tid;
    const int nr = idx >> 6, kc = idx & 63;
    dst[(size_t)(tc * 64 + nr) * DM + tr * 64 + kc] = tile[kc][nr];
  }
}

// W2s[g][b][n][k] = bf16( Wa2T[ruleBase+g][n][k] * cond[ruleBase+g][b][n] / 4096 )
__global__ __launch_bounds__(256) void scale_w2(const u16* __restrict__ WT,
                                                const float* __restrict__ cond,
                                                u16* __restrict__ W2s,
                                                int ruleBase, int G) {
  const int total = G * 4 * DM * (DM / 8);
  for (int idx = blockIdx.x * 256 + threadIdx.x; idx < total; idx += gridDim.x * 256) {
    const int k8 = idx & 63;
    const int n  = (idx >> 6) & (DM - 1);
    const int gb = idx >> 15;            // g*4+b   (64*512 = 2^15)
    const int g = gb >> 2, b = gb & 3, rule = ruleBase + g;
    const float c = cond[((size_t)rule * 4 + b) * DM + n] * (1.0f / 4096.0f);
    const uint4 w = *(const uint4*)&WT[((size_t)(32 + rule)) * DM * DM + (size_t)n * DM + k8 * 8];
    uint4 o;
    {
      uint32_t u;
      u = w.x; o.x = (uint32_t)f2bf(__uint_as_float(u << 16) * c) | ((uint32_t)f2bf(__uint_as_float(u & 0xffff0000u) * c) << 16);
      u = w.y; o.y = (uint32_t)f2bf(__uint_as_float(u << 16) * c) | ((uint32_t)f2bf(__uint_as_float(u & 0xffff0000u) * c) << 16);
      u = w.z; o.z = (uint32_t)f2bf(__uint_as_float(u << 16) * c) | ((uint32_t)f2bf(__uint_as_float(u & 0xffff0000u) * c) << 16);
      u = w.w; o.w = (uint32_t)f2bf(__uint_as_float(u << 16) * c) | ((uint32_t)f2bf(__uint_as_float(u & 0xffff0000u) * c) << 16);
    }
    *(uint4*)&W2s[(size_t)gb * DM * DM + (size_t)n * DM + k8 * 8] = o;
  }
}

// ---------------- phase 1: cond partial sums + H = silu(x@Wa1) ----------------
// 128x128 tile, 4 waves 2x2, BK=64.  32x32x16 MFMA: wave tile 64x64 = 2x2
// tiles of 32x32, acc floatx16[2][2].
// A/B lane map: row/col = lane&31, k = (lane>>5)*8 + j.
// C/D [m74/m101]: col = lane&31, row = (reg&3) + 8*(reg>>2) + 4*(lane>>5).

__global__ __launch_bounds__(256, 3) void p1_kernel(const u16* __restrict__ X,
                                                    const u16* __restrict__ WT,
                                                    const float* __restrict__ bc,
                                                    const float* __restrict__ ba1,
                                                    float* __restrict__ cond,
                                                    u16* __restrict__ H, int ruleBase) {
  __shared__ __attribute__((aligned(16))) u16 ldsA[128 * 64];
  __shared__ __attribute__((aligned(16))) u16 ldsB[128 * 64];
  const int tid = threadIdx.x;
  const int lane = tid & 63, wid = tid >> 6;
  const int waveM = wid >> 1, waveN = wid & 1;
  const int m0 = blockIdx.x * 128;
  const int nb = blockIdx.y;
  const int z = blockIdx.z;
  const int rule = ruleBase + z;
  const bool is_cond = nb < 4;
  const int n0 = (is_cond ? nb : nb - 4) * 128;
  const u16* B = WT + (size_t)(is_cond ? rule : 16 + rule) * (DM * DM);

  floatx16 acc[2][2];
#pragma unroll
  for (int i = 0; i < 2; i++)
#pragma unroll
    for (int j = 0; j < 2; j++) acc[i][j] = (floatx16)0.0f;

  const int l31 = lane & 31, lg = lane >> 5;

  for (int k0 = 0; k0 < DM; k0 += BK) {
    __syncthreads();
#pragma unroll
    for (int q = 0; q < 4; q++) stage32x64(X, DM, m0 + 32 * q, k0, ldsA + q * 2048, tid);
#pragma unroll
    for (int q = 0; q < 4; q++) stage32x64(B, DM, n0 + 32 * q, k0, ldsB + q * 2048, tid);
    __syncthreads();
#pragma unroll
    for (int s = 0; s < 4; s++) {
      const int c = s * 2 + lg;
      short8 a[2], bb[2];
#pragma unroll
      for (int i = 0; i < 2; i++) {
        const int row = waveM * 64 + i * 32 + l31;
        a[i] = *(const short8*)&ldsA[row * 64 + ((c ^ SW(row)) * 8)];
      }
#pragma unroll
      for (int j = 0; j < 2; j++) {
        const int row = waveN * 64 + j * 32 + l31;
        bb[j] = *(const short8*)&ldsB[row * 64 + ((c ^ SW(row)) * 8)];
      }
#pragma unroll
      for (int i = 0; i < 2; i++)
#pragma unroll
        for (int j = 0; j < 2; j++)
          acc[i][j] = __builtin_amdgcn_mfma_f32_32x32x16_bf16(a[i], bb[j], acc[i][j], 0, 0, 0);
    }
  }

  if (is_cond) {
    const int b = m0 >> 12;   // 128-row block lies within one batch
    float s[2];
#pragma unroll
    for (int j = 0; j < 2; j++) {
      const int col = n0 + waveN * 64 + j * 32 + l31;
      const float bias = bc[rule * DM + col];
      float tsum = 0.f;
#pragma unroll
      for (int i = 0; i < 2; i++)
#pragma unroll
        for (int r = 0; r < 16; r++)
          tsum += __builtin_amdgcn_rcpf(1.0f + __expf(-(acc[i][j][r] + bias)));
      s[j] = tsum;
    }
#pragma unroll
    for (int j = 0; j < 2; j++) s[j] += __shfl_xor(s[j], 32);
    if (lg == 0) {
#pragma unroll
      for (int j = 0; j < 2; j++) {
        const int col = n0 + waveN * 64 + j * 32 + l31;
        atomicAdd(&cond[((size_t)rule * 4 + b) * DM + col], s[j]);
      }
    }
  } else {
    u16* Hr = H + (size_t)z * M_TOTAL * DM;
#pragma unroll
    for (int i = 0; i < 2; i++)
#pragma unroll
      for (int j = 0; j < 2; j++) {
        const int col = n0 + waveN * 64 + j * 32 + l31;
        const float bias = ba1[rule * DM + col];
#pragma unroll
        for (int r = 0; r < 16; r++) {
          const int row = m0 + waveM * 64 + i * 32 + (r & 3) + 8 * (r >> 2) + 4 * lg;
          const float v = acc[i][j][r] + bias;
          Hr[(size_t)row * DM + col] = f2bf(v * __builtin_amdgcn_rcpf(1.0f + __expf(-v)));
        }
      }
  }
}

// ---------------- phase 2: out (+)= sum_g H_g @ W2s_g + sum_g cond_g*ba2_g ----------------
// W2s pre-scaled by cond/4096 -> one fused accumulator, K_eff = G*512.
// 128x128 tile, BK=128 (R7 win), 32x32x16 MFMA, SW swizzle.

__global__ __launch_bounds__(256, 2) void p2_kernel(const u16* __restrict__ H,
                                                    const u16* __restrict__ W2s,
                                                    const float* __restrict__ ba2,
                                                    const float* __restrict__ cond,
                                                    float* __restrict__ out,
                                                    int ruleBase, int G, int accumulate) {
  __shared__ __attribute__((aligned(16))) u16 ldsA[128 * 128];   // 32 KB
  __shared__ __attribute__((aligned(16))) u16 ldsB[128 * 128];   // 32 KB
  const int tid = threadIdx.x;
  const int lane = tid & 63, wid = tid >> 6;
  const int waveM = wid >> 1, waveN = wid & 1;
  const int m0 = blockIdx.x * 128;
  const int n0 = blockIdx.y * 128;
  const int b = m0 >> 12;
  const int l31 = lane & 31, lg = lane >> 5;

  floatx16 acc[2][2];
#pragma unroll
  for (int i = 0; i < 2; i++)
#pragma unroll
    for (int j = 0; j < 2; j++) acc[i][j] = (floatx16)0.0f;

  for (int g = 0; g < G; g++) {
    const u16* A = H + (size_t)g * M_TOTAL * DM;
    const u16* Bp = W2s + (size_t)(g * 4 + b) * (DM * DM);
    for (int k0 = 0; k0 < DM; k0 += 128) {
      __syncthreads();
#pragma unroll
      for (int q = 0; q < 8; q++) stage16x128(A, DM, m0 + 16 * q, k0, ldsA + q * 2048, tid);
#pragma unroll
      for (int q = 0; q < 8; q++) stage16x128(Bp, DM, n0 + 16 * q, k0, ldsB + q * 2048, tid);
      __syncthreads();
#pragma unroll
      for (int s = 0; s < 8; s++) {
        const int c = s * 2 + lg;
        short8 a[2], bb[2];
#pragma unroll
        for (int i = 0; i < 2; i++) {
          const int row = waveM * 64 + i * 32 + l31;
          a[i] = *(const short8*)&ldsA[row * 128 + ((c ^ SW(row)) * 8)];
        }
#pragma unroll
        for (int j = 0; j < 2; j++) {
          const int row = waveN * 64 + j * 32 + l31;
          bb[j] = *(const short8*)&ldsB[row * 128 + ((c ^ SW(row)) * 8)];
        }
#pragma unroll
        for (int i = 0; i < 2; i++)
#pragma unroll
          for (int j = 0; j < 2; j++)
            acc[i][j] = __builtin_amdgcn_mfma_f32_32x32x16_bf16(a[i], bb[j], acc[i][j], 0, 0, 0);
      }
    }
  }

#pragma unroll
  for (int j = 0; j < 2; j++) {
    const int col = n0 + waveN * 64 + j * 32 + l31;
    float bt = 0.f;
    for (int g = 0; g < G; g++) {
      const int rule = ruleBase + g;
      bt += cond[((size_t)rule * 4 + b) * DM + col] * ba2[rule * DM + col];
    }
    bt *= (1.0f / 4096.0f);
#pragma unroll
    for (int i = 0; i < 2; i++)
#pragma unroll
      for (int r = 0; r < 16; r++) {
        const int row = m0 + waveM * 64 + i * 32 + (r & 3) + 8 * (r >> 2) + 4 * lg;
        const size_t idx = (size_t)row * DM + col;
        const float v = acc[i][j][r] + bt;
        out[idx] = accumulate ? (out[idx] + v) : v;
      }
  }
}

// ---------------- launch ----------------

extern "C" void kernel_launch(void* const* d_in, const int* in_sizes, int n_in,
                              void* d_out, int out_size, void* d_ws, size_t ws_size,
                              hipStream_t stream) {
  const float* x   = (const float*)d_in[0];
  const float* Wc  = (const float*)d_in[1];
  const float* bc  = (const float*)d_in[2];
  const float* Wa1 = (const float*)d_in[3];
  const float* ba1 = (const float*)d_in[4];
  const float* Wa2 = (const float*)d_in[5];
  const float* ba2 = (const float*)d_in[6];
  float* out = (float*)d_out;

  char* ws = (char*)d_ws;
  const size_t xBytes = (size_t)M_TOTAL * DM * 2;          // 16.78 MB
  const size_t wtBytes = (size_t)48 * DM * DM * 2;         // 25.17 MB
  const size_t condBytes = (size_t)NRULES * 4 * DM * 4;    // 128 KB
  const size_t fixed = xBytes + wtBytes + condBytes;
  const size_t hSlice = (size_t)M_TOTAL * DM * 2;          // 16.78 MB
  const size_t w2sSlice = (size_t)4 * DM * DM * 2;         // 2.10 MB per rule

  int G = 1;
  const int cand[5] = {16, 8, 4, 2, 1};
  for (int i = 0; i < 5; i++) {
    if (fixed + (size_t)cand[i] * (hSlice + w2sSlice) <= ws_size) { G = cand[i]; break; }
  }

  u16* X      = (u16*)ws;
  u16* WT     = (u16*)(ws + xBytes);
  float* cond = (float*)(ws + xBytes + wtBytes);
  u16* W2s    = (u16*)(ws + fixed);
  u16* H      = (u16*)(ws + fixed + (size_t)G * w2sSlice);

  convert_x<<<dim3(2048), dim3(256), 0, stream>>>(x, X, cond);
  transpose_w<<<dim3(48 * 64), dim3(256), 0, stream>>>(Wc, Wa1, Wa2, WT);

  for (int rb = 0; rb < NRULES; rb += G) {
    p1_kernel<<<dim3(128, 8, G), dim3(256), 0, stream>>>(X, WT, bc, ba1, cond, H, rb);
    scale_w2<<<dim3(2048), dim3(256), 0, stream>>>(WT, cond, W2s, rb, G);
    p2_kernel<<<dim3(128, 4), dim3(256), 0, stream>>>(H, W2s, ba2, cond, out, rb, G, rb > 0 ? 1 : 0);
  }
}

// Round 10
// 568.566 us; speedup vs baseline: 1.1324x; 1.0795x over previous
//
#include <hip/hip_runtime.h>
#include <stdint.h>

typedef unsigned short u16;
typedef __attribute__((ext_vector_type(8))) short short8;
typedef __attribute__((ext_vector_type(4))) float floatx4;

#define M_TOTAL 16384   // BATCH*SEQ
#define DM 512
#define NRULES 16
#define BK 64

// Swizzle for p2's 128-col rows: SW(r)=(r>>1)&7 is conflict-free under both
// ds_read_b128 phase models (16-lane and even/odd grouping) — R9 measured 0.
#define SW(r) (((r) >> 1) & 7)

__device__ __forceinline__ u16 f2bf(float f) {
  uint32_t u = __float_as_uint(f);
  u += 0x7fffu + ((u >> 16) & 1u);   // RNE
  return (u16)(u >> 16);
}

__device__ __forceinline__ void gld_lds16(const u16* g, u16* l) {
  __builtin_amdgcn_global_load_lds(
      (const __attribute__((address_space(1))) void*)g,
      (__attribute__((address_space(3))) void*)l, 16, 0, 0);
}

// p1 staging: 32 rows x 64 cols, physical chunk p holds logical p^(row&7)
// (R7 pattern — measured 0 conflicts with the matching ((t*4+lq)^l7) reader).
__device__ __forceinline__ void stage32x64(const u16* __restrict__ src, int ld,
                                           int r0, int k0, u16* lds, int tid) {
  const int row = tid >> 3, p = tid & 7;
  const int g = p ^ (row & 7);
  gld_lds16(src + (size_t)(r0 + row) * ld + k0 + g * 8, lds + tid * 8);
}

// p2 staging (512 threads): 32 rows x 128 cols, chunk p^SW(row).
// Tile-row = 32q + local row; SW(32q+r) == SW(r) since 16q = 0 mod 8.
__device__ __forceinline__ void stage32x128_t512(const u16* __restrict__ src, int ld,
                                                 int r0, int k0, u16* lds, int tid) {
  const int row = tid >> 4, p = tid & 15;
  const int g = p ^ SW(row);
  gld_lds16(src + (size_t)(r0 + row) * ld + k0 + g * 8, lds + tid * 8);
}

// ---------------- conversion kernels ----------------

__global__ __launch_bounds__(256) void convert_x(const float* __restrict__ x,
                                                 u16* __restrict__ X,
                                                 float* __restrict__ cond) {
  const int gid = blockIdx.x * 256 + threadIdx.x;
  if (gid < NRULES * 4 * DM) cond[gid] = 0.f;   // zero cond accumulators (ws poisoned)
  const int n4 = M_TOTAL * DM / 4;
  for (int i = gid; i < n4; i += gridDim.x * 256) {
    float4 v = ((const float4*)x)[i];
    ushort4 o;
    o.x = f2bf(v.x); o.y = f2bf(v.y); o.z = f2bf(v.z); o.w = f2bf(v.w);
    ((ushort4*)X)[i] = o;
  }
}

// 48 matrices [512][512] fp32 (k-major) -> bf16 transposed [n][k].
// WT slots: 0..15 = Wc^T, 16..31 = Wa1^T, 32..47 = Wa2^T.
__global__ __launch_bounds__(256) void transpose_w(const float* __restrict__ Wc,
                                                   const float* __restrict__ Wa1,
                                                   const float* __restrict__ Wa2,
                                                   u16* __restrict__ WT) {
  __shared__ u16 tile[64][68];
  const int bx = blockIdx.x;            // 48*64
  const int m = bx >> 6, t = bx & 63;
  const int tr = t >> 3, tc = t & 7;    // 64x64 tile at (k=tr*64, n=tc*64)
  const float* src = (m < 16 ? Wc : (m < 32 ? Wa1 : Wa2)) + (size_t)(m & 15) * (DM * DM);
  const int tid = threadIdx.x;
#pragma unroll
  for (int rep = 0; rep < 16; rep++) {
    const int idx = rep * 256 + tid;
    const int kr = idx >> 6, nc = idx & 63;
    tile[kr][nc] = f2bf(src[(size_t)(tr * 64 + kr) * DM + tc * 64 + nc]);
  }
  __syncthreads();
  u16* dst = WT + (size_t)m * (DM * DM);
#pragma unroll
  for (int rep = 0; rep < 16; rep++) {
    const int idx = rep * 256 + tid;
    const int nr = idx >> 6, kc = idx & 63;
    dst[(size_t)(tc * 64 + nr) * DM + tr * 64 + kc] = tile[kc][nr];
  }
}

// W2s[g][b][n][k] = bf16( Wa2T[ruleBase+g][n][k] * cond[ruleBase+g][b][n] / 4096 )
__global__ __launch_bounds__(256) void scale_w2(const u16* __restrict__ WT,
                                                const float* __restrict__ cond,
                                                u16* __restrict__ W2s,
                                                int ruleBase, int G) {
  const int total = G * 4 * DM * (DM / 8);
  for (int idx = blockIdx.x * 256 + threadIdx.x; idx < total; idx += gridDim.x * 256) {
    const int k8 = idx & 63;
    const int n  = (idx >> 6) & (DM - 1);
    const int gb = idx >> 15;            // g*4+b   (64*512 = 2^15)
    const int g = gb >> 2, b = gb & 3, rule = ruleBase + g;
    const float c = cond[((size_t)rule * 4 + b) * DM + n] * (1.0f / 4096.0f);
    const uint4 w = *(const uint4*)&WT[((size_t)(32 + rule)) * DM * DM + (size_t)n * DM + k8 * 8];
    uint4 o;
    {
      uint32_t u;
      u = w.x; o.x = (uint32_t)f2bf(__uint_as_float(u << 16) * c) | ((uint32_t)f2bf(__uint_as_float(u & 0xffff0000u) * c) << 16);
      u = w.y; o.y = (uint32_t)f2bf(__uint_as_float(u << 16) * c) | ((uint32_t)f2bf(__uint_as_float(u & 0xffff0000u) * c) << 16);
      u = w.z; o.z = (uint32_t)f2bf(__uint_as_float(u << 16) * c) | ((uint32_t)f2bf(__uint_as_float(u & 0xffff0000u) * c) << 16);
      u = w.w; o.w = (uint32_t)f2bf(__uint_as_float(u << 16) * c) | ((uint32_t)f2bf(__uint_as_float(u & 0xffff0000u) * c) << 16);
    }
    *(uint4*)&W2s[(size_t)gb * DM * DM + (size_t)n * DM + k8 * 8] = o;
  }
}

// ---------------- phase 1: cond partial sums + H = silu(x@Wa1) ----------------
// Byte-exact R7 config: 128x128 tile, 4 waves 2x2, BK=64, 16x16x32 MFMA,
// (256,3).  958 TF measured; 32x32x16 variant (R8/R9) regressed via
// accumulator-chain dependency stalls — do not revisit.

__global__ __launch_bounds__(256, 3) void p1_kernel(const u16* __restrict__ X,
                                                    const u16* __restrict__ WT,
                                                    const float* __restrict__ bc,
                                                    const float* __restrict__ ba1,
                                                    float* __restrict__ cond,
                                                    u16* __restrict__ H, int ruleBase) {
  __shared__ __attribute__((aligned(16))) u16 ldsA[128 * 64];
  __shared__ __attribute__((aligned(16))) u16 ldsB[128 * 64];
  const int tid = threadIdx.x;
  const int lane = tid & 63, wid = tid >> 6;
  const int waveM = wid >> 1, waveN = wid & 1;
  const int m0 = blockIdx.x * 128;
  const int nb = blockIdx.y;
  const int z = blockIdx.z;
  const int rule = ruleBase + z;
  const bool is_cond = nb < 4;
  const int n0 = (is_cond ? nb : nb - 4) * 128;
  const u16* B = WT + (size_t)(is_cond ? rule : 16 + rule) * (DM * DM);

  floatx4 acc[4][4];
#pragma unroll
  for (int i = 0; i < 4; i++)
#pragma unroll
    for (int j = 0; j < 4; j++) acc[i][j] = (floatx4)0.0f;

  const int lm = lane & 15, lq = lane >> 4, l7 = lane & 7;

  for (int k0 = 0; k0 < DM; k0 += BK) {
    __syncthreads();
#pragma unroll
    for (int q = 0; q < 4; q++) stage32x64(X, DM, m0 + 32 * q, k0, ldsA + q * 2048, tid);
#pragma unroll
    for (int q = 0; q < 4; q++) stage32x64(B, DM, n0 + 32 * q, k0, ldsB + q * 2048, tid);
    __syncthreads();
#pragma unroll
    for (int t = 0; t < 2; t++) {
      const int co = ((t * 4 + lq) ^ l7) * 8;
      short8 a[4], bb[4];
#pragma unroll
      for (int i = 0; i < 4; i++)
        a[i] = *(const short8*)&ldsA[(waveM * 64 + i * 16 + lm) * 64 + co];
#pragma unroll
      for (int j = 0; j < 4; j++)
        bb[j] = *(const short8*)&ldsB[(waveN * 64 + j * 16 + lm) * 64 + co];
#pragma unroll
      for (int i = 0; i < 4; i++)
#pragma unroll
        for (int j = 0; j < 4; j++)
          acc[i][j] = __builtin_amdgcn_mfma_f32_16x16x32_bf16(a[i], bb[j], acc[i][j], 0, 0, 0);
    }
  }

  if (is_cond) {
    const int b = m0 >> 12;   // 128-row block lies within one batch
    float s[4];
#pragma unroll
    for (int j = 0; j < 4; j++) {
      const int col = n0 + waveN * 64 + j * 16 + lm;
      const float bias = bc[rule * DM + col];
      float tsum = 0.f;
#pragma unroll
      for (int i = 0; i < 4; i++)
#pragma unroll
        for (int r = 0; r < 4; r++)
          tsum += __builtin_amdgcn_rcpf(1.0f + __expf(-(acc[i][j][r] + bias)));
      s[j] = tsum;
    }
#pragma unroll
    for (int j = 0; j < 4; j++) {          // reduce across quads (rows)
      s[j] += __shfl_xor(s[j], 16);
      s[j] += __shfl_xor(s[j], 32);
    }
    if (lq == 0) {
#pragma unroll
      for (int j = 0; j < 4; j++) {
        const int col = n0 + waveN * 64 + j * 16 + lm;
        atomicAdd(&cond[((size_t)rule * 4 + b) * DM + col], s[j]);
      }
    }
  } else {
    u16* Hr = H + (size_t)z * M_TOTAL * DM;
#pragma unroll
    for (int i = 0; i < 4; i++)
#pragma unroll
      for (int j = 0; j < 4; j++) {
        const int col = n0 + waveN * 64 + j * 16 + lm;
        const float bias = ba1[rule * DM + col];
#pragma unroll
        for (int r = 0; r < 4; r++) {
          const int row = m0 + waveM * 64 + i * 16 + lq * 4 + r;
          const float v = acc[i][j][r] + bias;
          Hr[(size_t)row * DM + col] = f2bf(v * __builtin_amdgcn_rcpf(1.0f + __expf(-v)));
        }
      }
  }
}

// ---------------- phase 2: out (+)= sum_g H_g @ W2s_g + sum_g cond_g*ba2_g ----------------
// W2s pre-scaled by cond/4096 -> one fused accumulator, K_eff = G*512.
// 128x128 tile, BK=128 (R7 win), 16x16x32 MFMA.
// NEW: 512-thread blocks (8 waves, 2x4 wave grid, wave tile 64x32).
// Grid stays 512 = 2 blocks/CU (its hard ceiling), but waves/CU doubles
// 8 -> 16 with IDENTICAL tile traffic — attacks p2's exposed-latency gap
// (570 TF vs p1's 958) without R4/R5/R6's failure modes.
// __launch_bounds__(512,4): 2 blocks x 8 waves / 4 EU = 4 waves/EU, <=128 VGPR
// (acc 32 AGPR + 24 frag VGPR + addressing fits).

__global__ __launch_bounds__(512, 4) void p2_kernel(const u16* __restrict__ H,
                                                    const u16* __restrict__ W2s,
                                                    const float* __restrict__ ba2,
                                                    const float* __restrict__ cond,
                                                    float* __restrict__ out,
                                                    int ruleBase, int G, int accumulate) {
  __shared__ __attribute__((aligned(16))) u16 ldsA[128 * 128];   // 32 KB
  __shared__ __attribute__((aligned(16))) u16 ldsB[128 * 128];   // 32 KB
  const int tid = threadIdx.x;                 // 0..511
  const int lane = tid & 63, wid = tid >> 6;   // 8 waves
  const int waveM = wid >> 2, waveN = wid & 3; // 2 x 4, wave tile 64x32
  const int m0 = blockIdx.x * 128;
  const int n0 = blockIdx.y * 128;
  const int b = m0 >> 12;
  const int lm = lane & 15, lq = lane >> 4;

  floatx4 acc[4][2];
#pragma unroll
  for (int i = 0; i < 4; i++)
#pragma unroll
    for (int j = 0; j < 2; j++) acc[i][j] = (floatx4)0.0f;

  for (int g = 0; g < G; g++) {
    const u16* A = H + (size_t)g * M_TOTAL * DM;
    const u16* Bp = W2s + (size_t)(g * 4 + b) * (DM * DM);
    for (int k0 = 0; k0 < DM; k0 += 128) {
      __syncthreads();
#pragma unroll
      for (int q = 0; q < 4; q++) stage32x128_t512(A, DM, m0 + 32 * q, k0, ldsA + q * 4096, tid);
#pragma unroll
      for (int q = 0; q < 4; q++) stage32x128_t512(Bp, DM, n0 + 32 * q, k0, ldsB + q * 4096, tid);
      __syncthreads();
#pragma unroll
      for (int kk = 0; kk < 4; kk++) {
        const int c = kk * 4 + lq;
        short8 a[4], bb[2];
#pragma unroll
        for (int i = 0; i < 4; i++) {
          const int row = waveM * 64 + i * 16 + lm;
          a[i] = *(const short8*)&ldsA[row * 128 + ((c ^ SW(row)) * 8)];
        }
#pragma unroll
        for (int j = 0; j < 2; j++) {
          const int row = waveN * 32 + j * 16 + lm;
          bb[j] = *(const short8*)&ldsB[row * 128 + ((c ^ SW(row)) * 8)];
        }
#pragma unroll
        for (int i = 0; i < 4; i++)
#pragma unroll
          for (int j = 0; j < 2; j++)
            acc[i][j] = __builtin_amdgcn_mfma_f32_16x16x32_bf16(a[i], bb[j], acc[i][j], 0, 0, 0);
      }
    }
  }

#pragma unroll
  for (int j = 0; j < 2; j++) {
    const int col = n0 + waveN * 32 + j * 16 + lm;
    float bt = 0.f;
    for (int g = 0; g < G; g++) {
      const int rule = ruleBase + g;
      bt += cond[((size_t)rule * 4 + b) * DM + col] * ba2[rule * DM + col];
    }
    bt *= (1.0f / 4096.0f);
#pragma unroll
    for (int i = 0; i < 4; i++)
#pragma unroll
      for (int r = 0; r < 4; r++) {
        const int row = m0 + waveM * 64 + i * 16 + lq * 4 + r;
        const size_t idx = (size_t)row * DM + col;
        const float v = acc[i][j][r] + bt;
        out[idx] = accumulate ? (out[idx] + v) : v;
      }
  }
}

// ---------------- launch ----------------

extern "C" void kernel_launch(void* const* d_in, const int* in_sizes, int n_in,
                              void* d_out, int out_size, void* d_ws, size_t ws_size,
                              hipStream_t stream) {
  const float* x   = (const float*)d_in[0];
  const float* Wc  = (const float*)d_in[1];
  const float* bc  = (const float*)d_in[2];
  const float* Wa1 = (const float*)d_in[3];
  const float* ba1 = (const float*)d_in[4];
  const float* Wa2 = (const float*)d_in[5];
  const float* ba2 = (const float*)d_in[6];
  float* out = (float*)d_out;

  char* ws = (char*)d_ws;
  const size_t xBytes = (size_t)M_TOTAL * DM * 2;          // 16.78 MB
  const size_t wtBytes = (size_t)48 * DM * DM * 2;         // 25.17 MB
  const size_t condBytes = (size_t)NRULES * 4 * DM * 4;    // 128 KB
  const size_t fixed = xBytes + wtBytes + condBytes;
  const size_t hSlice = (size_t)M_TOTAL * DM * 2;          // 16.78 MB
  const size_t w2sSlice = (size_t)4 * DM * DM * 2;         // 2.10 MB per rule

  int G = 1;
  const int cand[5] = {16, 8, 4, 2, 1};
  for (int i = 0; i < 5; i++) {
    if (fixed + (size_t)cand[i] * (hSlice + w2sSlice) <= ws_size) { G = cand[i]; break; }
  }

  u16* X      = (u16*)ws;
  u16* WT     = (u16*)(ws + xBytes);
  float* cond = (float*)(ws + xBytes + wtBytes);
  u16* W2s    = (u16*)(ws + fixed);
  u16* H      = (u16*)(ws + fixed + (size_t)G * w2sSlice);

  convert_x<<<dim3(2048), dim3(256), 0, stream>>>(x, X, cond);
  transpose_w<<<dim3(48 * 64), dim3(256), 0, stream>>>(Wc, Wa1, Wa2, WT);

  for (int rb = 0; rb < NRULES; rb += G) {
    p1_kernel<<<dim3(128, 8, G), dim3(256), 0, stream>>>(X, WT, bc, ba1, cond, H, rb);
    scale_w2<<<dim3(2048), dim3(256), 0, stream>>>(WT, cond, W2s, rb, G);
    p2_kernel<<<dim3(128, 4), dim3(512), 0, stream>>>(H, W2s, ba2, cond, out, rb, G, rb > 0 ? 1 : 0);
  }
}